// Round 1
// baseline (100.165 us; speedup 1.0000x reference)
//
#include <hip/hip_runtime.h>
#include <math.h>

#define BATCH 32
#define CCH 3
#define HH 256
#define WW 256
#define HW (HH*WW)
#define NGN_IT 5
#define NM 45            // 21 (A sym 6x6) + 6 (q0) + 18 (R0 3x6)
#define NBLK 64
#define NTHR 256
#define PPT (HW/(NBLK*NTHR))   // 4 pixels per thread

__host__ __device__ constexpr int idxA(int i, int j) { return 6*i - i*(i+1)/2 + j; } // i<=j

// ---------------------------------------------------------------------------
// Stage 1: per-(batch, block) partial moments. Deterministic (no atomics).
// Moments (per batch, masked pixels only):
//   A[i][j]  = sum_{p,c} J0[c,i]*J0[c,j]          (sym, 21)
//   q0[s]    = sum_{p,c} J0[c,s]*d[c]             (6),  d = f_inp - base_feat
//   R0[c][s] = sum_{p}   J0[c,s]                  (18)
// where J0 = G * Jc0, G = spatial grad of base_feat (batch-independent),
// Jc0 = [-Jp*S(Xc) | Jp]. Note M = G*Jp == J0[:,3:6], so the t-dependent
// bilinear terms of JtJ/Jte are all recoverable from A, q0, R0.
// ---------------------------------------------------------------------------
__global__ __launch_bounds__(NTHR) void k_moments(
    const float* __restrict__ f_inp, const float* __restrict__ depth,
    const int* __restrict__ fidx, const float* __restrict__ Kmat,
    const float* __restrict__ bbox, const float* __restrict__ base_feat,
    float* __restrict__ partials)
{
    const int b   = blockIdx.y;
    const int blk = blockIdx.x;
    const int tid = threadIdx.x;

    const float fx = Kmat[b*9+0], fy = Kmat[b*9+4];
    const float cx = Kmat[b*9+2], cy = Kmat[b*9+5];
    const float bb0 = bbox[b*2+0], bb1 = bbox[b*2+1];
    const float* __restrict__ dpt = depth + (size_t)b*HW;
    const int*   __restrict__ msk = fidx  + (size_t)b*HW;
    const float* __restrict__ fin = f_inp + (size_t)b*CCH*HW;

    float acc[NM];
    #pragma unroll
    for (int k = 0; k < NM; ++k) acc[k] = 0.f;

    #pragma unroll
    for (int it = 0; it < PPT; ++it) {
        const int p = blk*NTHR + tid + it*(NBLK*NTHR);
        if (msk[p] >= 0) {
            const int h = p >> 8, w = p & (WW-1);
            const float z = dpt[p];
            const float inv_z = 1.0f / z;
            const float du = bb0 + (float)w - cx;
            const float dv = bb1 + (float)h - cy;
            const float a_ = fx*inv_z, b_ = fy*inv_z;       // Jp[0][0], Jp[1][1]
            const float cu = -du*inv_z, cv = -dv*inv_z;     // Jp[0][2], Jp[1][2]
            const float xc = du*z/fx, yc = dv*z/fy;
            // Jc0 = [-Jp*S(xc,yc,z) | Jp], rows:
            const float r00 = cu*yc;
            const float r01 = a_*z - cu*xc;
            const float r02 = -a_*yc;
            const float r10 = cv*yc - b_*z;
            const float r11 = -cv*xc;
            const float r12 = b_*xc;
            // gradient stencil indices (clamped -> edge one-sided with scale 1)
            const int pl = (w==0)     ? p : p-1;
            const int pr = (w==WW-1)  ? p : p+1;
            const int pd = (h==0)     ? p : p-WW;
            const int pu = (h==HH-1)  ? p : p+WW;
            const float sx = (w==0 || w==WW-1) ? 1.0f : 0.5f;
            const float sy = (h==0 || h==HH-1) ? 1.0f : 0.5f;
            #pragma unroll
            for (int c = 0; c < CCH; ++c) {
                const float* __restrict__ bfc = base_feat + (size_t)c*HW;
                const float ctr = bfc[p];
                const float gx = (bfc[pr] - bfc[pl]) * sx;
                const float gy = (bfc[pu] - bfc[pd]) * sy;
                const float d  = fin[(size_t)c*HW + p] - ctr;
                float J0[6];
                J0[0] = gx*r00 + gy*r10;
                J0[1] = gx*r01 + gy*r11;
                J0[2] = gx*r02 + gy*r12;
                J0[3] = gx*a_;
                J0[4] = gy*b_;
                J0[5] = gx*cu + gy*cv;
                #pragma unroll
                for (int i = 0; i < 6; ++i)
                    #pragma unroll
                    for (int j = i; j < 6; ++j)
                        acc[idxA(i,j)] += J0[i]*J0[j];
                #pragma unroll
                for (int s = 0; s < 6; ++s) acc[21 + s] += J0[s]*d;
                #pragma unroll
                for (int s = 0; s < 6; ++s) acc[27 + c*6 + s] += J0[s];
            }
        }
    }

    // block reduction: wave shuffle tree (deterministic) then 4-wave sum
    __shared__ float red[4*NM];
    const int lane = tid & 63;
    const int wave = tid >> 6;
    #pragma unroll
    for (int k = 0; k < NM; ++k) {
        float v = acc[k];
        #pragma unroll
        for (int off = 32; off > 0; off >>= 1) v += __shfl_down(v, off, 64);
        if (lane == 0) red[wave*NM + k] = v;
    }
    __syncthreads();
    if (tid < NM) {
        float s = red[tid] + red[NM + tid] + red[2*NM + tid] + red[3*NM + tid];
        partials[((size_t)b*NBLK + blk)*NM + tid] = s;
    }
}

// ---------------------------------------------------------------------------
// Stage 2: deterministic fp64 reduction of block partials -> per-batch moments
// ---------------------------------------------------------------------------
__global__ void k_reduce(const float* __restrict__ partials, double* __restrict__ moments)
{
    const int b = blockIdx.x, tid = threadIdx.x;
    if (tid < NM) {
        double s = 0.0;
        const float* p = partials + (size_t)b*NBLK*NM + tid;
        for (int blk = 0; blk < NBLK; ++blk) s += (double)p[(size_t)blk*NM];
        moments[(size_t)b*NM + tid] = s;
    }
}

// ---------------------------------------------------------------------------
// Stage 3: 5 GN iterations per batch in moment space (fp64), 1 thread/batch.
//   J(t) = J0 + M*S(t) on first 3 cols, M = J0[:,3:6]:
//   JtJ_tl = A_tl + P*S + (P*S)^T + S^T*A_br*S   (P = A_tr)
//   JtJ_tr = A_tr + S^T*A_br                     (A_br symmetric)
//   JtJ_br = A_br ;  + damping*I
//   Jte_b  = q0_b - sum_c tau_c R0[c,3:]  (= w3)
//   Jte_a  = q0_a - sum_c tau_c R0[c,:3] + S^T*w3
// ---------------------------------------------------------------------------
__global__ void k_gn(const double* __restrict__ moments,
                     const float* __restrict__ x_ini,
                     const float* __restrict__ W_pose,
                     const float* __restrict__ lam,
                     float* __restrict__ out)
{
    const int b = threadIdx.x;
    if (b >= BATCH) return;
    const double* mo = moments + (size_t)b*NM;

    double A[6][6];
    for (int i = 0; i < 6; ++i)
        for (int j = i; j < 6; ++j) { double v = mo[idxA(i,j)]; A[i][j] = v; A[j][i] = v; }
    double q0[6];
    for (int s = 0; s < 6; ++s) q0[s] = mo[21 + s];
    double R0[3][6];
    for (int c = 0; c < 3; ++c) for (int s = 0; s < 6; ++s) R0[c][s] = mo[27 + c*6 + s];
    double Wp[3][6];
    for (int c = 0; c < 3; ++c) for (int s = 0; s < 6; ++s) Wp[c][s] = (double)W_pose[c*6 + s];
    double x[6];
    for (int s = 0; s < 6; ++s) x[s] = (double)x_ini[b*6 + s];
    const double damping = log1p(exp((double)lam[0])) + 1e-6;

    for (int it = 0; it < NGN_IT; ++it) {
        double tau[3];
        for (int c = 0; c < 3; ++c) {
            double a = 0.0;
            for (int s = 0; s < 6; ++s) a += x[s]*Wp[c][s];
            tau[c] = tanh(a);
        }
        const double t0 = x[3], t1 = x[4], t2 = x[5];
        const double S[3][3] = {{0.0, -t2, t1}, {t2, 0.0, -t0}, {-t1, t0, 0.0}};

        double M[6][7];
        double PS[3][3], BS[3][3];
        for (int i = 0; i < 3; ++i) for (int j = 0; j < 3; ++j) {
            double s1 = 0.0, s2 = 0.0;
            for (int k = 0; k < 3; ++k) { s1 += A[i][3+k]*S[k][j]; s2 += A[3+i][3+k]*S[k][j]; }
            PS[i][j] = s1; BS[i][j] = s2;
        }
        for (int i = 0; i < 3; ++i) for (int j = 0; j < 3; ++j) {
            double st = 0.0;
            for (int k = 0; k < 3; ++k) st += S[k][i]*BS[k][j];
            M[i][j] = A[i][j] + PS[i][j] + PS[j][i] + st;
        }
        for (int i = 0; i < 3; ++i) for (int j = 0; j < 3; ++j) {
            double tr = A[i][3+j];
            for (int k = 0; k < 3; ++k) tr += S[k][i]*A[3+k][3+j];
            M[i][3+j] = tr; M[3+j][i] = tr;
        }
        for (int i = 0; i < 3; ++i) for (int j = 0; j < 3; ++j) M[3+i][3+j] = A[3+i][3+j];
        for (int d_ = 0; d_ < 6; ++d_) M[d_][d_] += damping;

        double base[6];
        for (int s = 0; s < 6; ++s) {
            double v = q0[s];
            for (int c = 0; c < 3; ++c) v -= tau[c]*R0[c][s];
            base[s] = v;
        }
        for (int s = 0; s < 3; ++s) {
            double v = base[s];
            for (int k = 0; k < 3; ++k) v += S[k][s]*base[3+k];
            M[s][6] = v;
        }
        for (int s = 3; s < 6; ++s) M[s][6] = base[s];

        // Gaussian elimination with partial pivoting (matches LU solve to rounding)
        for (int col = 0; col < 6; ++col) {
            int piv = col; double pv = fabs(M[col][col]);
            for (int r = col+1; r < 6; ++r) { double aa = fabs(M[r][col]); if (aa > pv) { pv = aa; piv = r; } }
            if (piv != col)
                for (int cc = col; cc < 7; ++cc) { double tmp = M[col][cc]; M[col][cc] = M[piv][cc]; M[piv][cc] = tmp; }
            const double inv = 1.0 / M[col][col];
            for (int r = col+1; r < 6; ++r) {
                const double f = M[r][col]*inv;
                for (int cc = col; cc < 7; ++cc) M[r][cc] -= f*M[col][cc];
            }
        }
        double sol[6];
        for (int r = 5; r >= 0; --r) {
            double s = M[r][6];
            for (int cc = r+1; cc < 6; ++cc) s -= M[r][cc]*sol[cc];
            sol[r] = s / M[r][r];
        }
        for (int s = 0; s < 6; ++s) x[s] += sol[s];
    }
    for (int s = 0; s < 6; ++s) out[b*6 + s] = (float)x[s];
}

extern "C" void kernel_launch(void* const* d_in, const int* in_sizes, int n_in,
                              void* d_out, int out_size, void* d_ws, size_t ws_size,
                              hipStream_t stream)
{
    (void)in_sizes; (void)n_in; (void)out_size; (void)ws_size;
    const float* f_inp = (const float*)d_in[0];
    const float* x_ini = (const float*)d_in[1];
    const float* depth = (const float*)d_in[2];
    const int*   fidx  = (const int*)  d_in[3];
    const float* Kmat  = (const float*)d_in[4];
    const float* bbox  = (const float*)d_in[5];
    const float* Wp    = (const float*)d_in[6];
    const float* bfeat = (const float*)d_in[7];
    const float* lam   = (const float*)d_in[8];
    float* out = (float*)d_out;

    float* partials = (float*)d_ws;
    const size_t part_bytes = (((size_t)BATCH*NBLK*NM*sizeof(float)) + 255) & ~(size_t)255;
    double* moments = (double*)((char*)d_ws + part_bytes);

    dim3 gB(NBLK, BATCH);
    k_moments<<<gB, NTHR, 0, stream>>>(f_inp, depth, fidx, Kmat, bbox, bfeat, partials);
    k_reduce<<<BATCH, 64, 0, stream>>>(partials, moments);
    k_gn<<<1, 64, 0, stream>>>(moments, x_ini, Wp, lam, out);
}

// Round 2
// 60.913 us; speedup vs baseline: 1.6444x; 1.6444x over previous
//
#include <hip/hip_runtime.h>
#include <math.h>

#define BATCH 32
#define CCH 3
#define HH 256
#define WW 256
#define HW (HH*WW)
#define NGN_IT 5
#define NM 45            // 21 (A sym 6x6) + 6 (q0) + 18 (R0 3x6)
#define NBLK 64
#define NTHR 256

__host__ __device__ constexpr int idxA(int i, int j) { return 6*i - i*(i+1)/2 + j; } // i<=j

// ---------------------------------------------------------------------------
// Stage 1: per-(batch, block) partial moments. Deterministic (no atomics).
// Each thread owns a quad of 4 contiguous pixels -> float4 loads.
// Moments (per batch, masked pixels only):
//   A[i][j]  = sum_{p,c} J0[c,i]*J0[c,j]          (sym, 21)
//   q0[s]    = sum_{p,c} J0[c,s]*d[c]             (6),  d = f_inp - base_feat
//   R0[c][s] = sum_{p}   J0[c,s]                  (18)
// ---------------------------------------------------------------------------
__global__ __launch_bounds__(NTHR) void k_moments(
    const float* __restrict__ f_inp, const float* __restrict__ depth,
    const int* __restrict__ fidx, const float* __restrict__ Kmat,
    const float* __restrict__ bbox, const float* __restrict__ base_feat,
    float* __restrict__ partials)
{
    const int b   = blockIdx.y;
    const int blk = blockIdx.x;
    const int tid = threadIdx.x;

    const float fx = Kmat[b*9+0], fy = Kmat[b*9+4];
    const float cx = Kmat[b*9+2], cy = Kmat[b*9+5];
    const float bb0 = bbox[b*2+0], bb1 = bbox[b*2+1];
    const float* __restrict__ dpt = depth + (size_t)b*HW;
    const int*   __restrict__ msk = fidx  + (size_t)b*HW;
    const float* __restrict__ fin = f_inp + (size_t)b*CCH*HW;

    const int qid = blk*NTHR + tid;     // quad index within image
    const int p0  = qid * 4;            // first pixel of quad (16B aligned)
    const int h   = p0 >> 8;
    const int w0  = p0 & (WW-1);        // 0..252, multiple of 4

    // quad-wide loads
    const float4 zv = *(const float4*)(dpt + p0);
    const int4   mv = *(const int4*)(msk + p0);
    float zq[4] = {zv.x, zv.y, zv.z, zv.w};
    float mq[4] = {mv.x >= 0 ? 1.f : 0.f, mv.y >= 0 ? 1.f : 0.f,
                   mv.z >= 0 ? 1.f : 0.f, mv.w >= 0 ? 1.f : 0.f};

    const float sy  = (h == 0 || h == HH-1) ? 1.0f : 0.5f;
    const float sx0 = (w0 == 0)     ? 1.0f : 0.5f;
    const float sx3 = (w0 == WW-4)  ? 1.0f : 0.5f;

    float ctr[CCH][4], gxq[CCH][4], gyq[CCH][4], dq[CCH][4];
    #pragma unroll
    for (int c = 0; c < CCH; ++c) {
        const float* __restrict__ bfc = base_feat + (size_t)c*HW;
        const float4 cv4 = *(const float4*)(bfc + p0);
        const float cc0 = cv4.x, cc1 = cv4.y, cc2 = cv4.z, cc3 = cv4.w;
        const float lf = (w0 == 0)    ? cc0 : bfc[p0 - 1];
        const float rt = (w0 == WW-4) ? cc3 : bfc[p0 + 4];
        const float4 up4 = (h == HH-1) ? cv4 : *(const float4*)(bfc + p0 + WW);
        const float4 dn4 = (h == 0)    ? cv4 : *(const float4*)(bfc + p0 - WW);
        const float4 fv4 = *(const float4*)(fin + (size_t)c*HW + p0);
        ctr[c][0]=cc0; ctr[c][1]=cc1; ctr[c][2]=cc2; ctr[c][3]=cc3;
        gxq[c][0] = (cc1 - lf ) * sx0;
        gxq[c][1] = (cc2 - cc0) * 0.5f;
        gxq[c][2] = (cc3 - cc1) * 0.5f;
        gxq[c][3] = (rt  - cc2) * sx3;
        gyq[c][0] = (up4.x - dn4.x) * sy;
        gyq[c][1] = (up4.y - dn4.y) * sy;
        gyq[c][2] = (up4.z - dn4.z) * sy;
        gyq[c][3] = (up4.w - dn4.w) * sy;
        dq[c][0] = fv4.x - cc0; dq[c][1] = fv4.y - cc1;
        dq[c][2] = fv4.z - cc2; dq[c][3] = fv4.w - cc3;
    }

    float acc[NM];
    #pragma unroll
    for (int k = 0; k < NM; ++k) acc[k] = 0.f;

    const float dv_ = bb1 + (float)h - cy;
    #pragma unroll
    for (int j = 0; j < 4; ++j) {
        const float z = zq[j];
        const float inv_z = 1.0f / z;
        const float du = bb0 + (float)(w0 + j) - cx;
        const float a_ = fx*inv_z, b_ = fy*inv_z;       // Jp[0][0], Jp[1][1]
        const float cu = -du*inv_z, cv = -dv_*inv_z;    // Jp[0][2], Jp[1][2]
        const float xc = du*z/fx, yc = dv_*z/fy;
        // Jc0 = [-Jp*S(xc,yc,z) | Jp], rows:
        const float r00 = cu*yc;
        const float r01 = a_*z - cu*xc;
        const float r02 = -a_*yc;
        const float r10 = cv*yc - b_*z;
        const float r11 = -cv*xc;
        const float r12 = b_*xc;
        const float m = mq[j];
        #pragma unroll
        for (int c = 0; c < CCH; ++c) {
            const float gx = gxq[c][j] * m;
            const float gy = gyq[c][j] * m;
            const float d  = dq[c][j];
            float J0[6];
            J0[0] = gx*r00 + gy*r10;
            J0[1] = gx*r01 + gy*r11;
            J0[2] = gx*r02 + gy*r12;
            J0[3] = gx*a_;
            J0[4] = gy*b_;
            J0[5] = gx*cu + gy*cv;
            #pragma unroll
            for (int i = 0; i < 6; ++i)
                #pragma unroll
                for (int jj = i; jj < 6; ++jj)
                    acc[idxA(i,jj)] += J0[i]*J0[jj];
            #pragma unroll
            for (int s = 0; s < 6; ++s) acc[21 + s] += J0[s]*d;
            #pragma unroll
            for (int s = 0; s < 6; ++s) acc[27 + c*6 + s] += J0[s];
        }
    }

    // block reduction: wave shuffle tree (deterministic) then 4-wave sum
    __shared__ float red[4*NM];
    const int lane = tid & 63;
    const int wave = tid >> 6;
    #pragma unroll
    for (int k = 0; k < NM; ++k) {
        float v = acc[k];
        #pragma unroll
        for (int off = 32; off > 0; off >>= 1) v += __shfl_down(v, off, 64);
        if (lane == 0) red[wave*NM + k] = v;
    }
    __syncthreads();
    if (tid < NM) {
        float s = red[tid] + red[NM + tid] + red[2*NM + tid] + red[3*NM + tid];
        partials[((size_t)b*NBLK + blk)*NM + tid] = s;
    }
}

// ---------------------------------------------------------------------------
// Stage 2 (fused): deterministic reduction of block partials + 5 GN
// iterations per batch in fp32 (dx ~ 1e-5, precision non-critical; JtJ is
// SPD so pivot-free elimination is exact enough and divergence-free).
// ---------------------------------------------------------------------------
__global__ __launch_bounds__(256) void k_solve(
    const float* __restrict__ partials,
    const float* __restrict__ x_ini,
    const float* __restrict__ W_pose,
    const float* __restrict__ lam,
    float* __restrict__ out)
{
    __shared__ float mom[BATCH][NM];
    const int tid = threadIdx.x;
    for (int idx = tid; idx < BATCH*NM; idx += 256) {
        const int b = idx / NM, k = idx % NM;
        double s = 0.0;
        const float* p = partials + ((size_t)b*NBLK)*NM + k;
        for (int blk = 0; blk < NBLK; ++blk) s += (double)p[(size_t)blk*NM];
        mom[b][k] = (float)s;
    }
    __syncthreads();

    const int b = tid;
    if (b >= BATCH) return;

    float A[6][6];
    for (int i = 0; i < 6; ++i)
        for (int j = i; j < 6; ++j) { float v = mom[b][idxA(i,j)]; A[i][j] = v; A[j][i] = v; }
    float q0[6];
    for (int s = 0; s < 6; ++s) q0[s] = mom[b][21 + s];
    float R0[3][6];
    for (int c = 0; c < 3; ++c) for (int s = 0; s < 6; ++s) R0[c][s] = mom[b][27 + c*6 + s];
    float Wp[3][6];
    for (int c = 0; c < 3; ++c) for (int s = 0; s < 6; ++s) Wp[c][s] = W_pose[c*6 + s];
    float x[6];
    for (int s = 0; s < 6; ++s) x[s] = x_ini[b*6 + s];
    const float damping = log1pf(expf(lam[0])) + 1e-6f;

    for (int it = 0; it < NGN_IT; ++it) {
        float tau[3];
        #pragma unroll
        for (int c = 0; c < 3; ++c) {
            float a = 0.f;
            #pragma unroll
            for (int s = 0; s < 6; ++s) a += x[s]*Wp[c][s];
            tau[c] = tanhf(a);
        }
        const float t0 = x[3], t1 = x[4], t2 = x[5];
        const float S[3][3] = {{0.f, -t2, t1}, {t2, 0.f, -t0}, {-t1, t0, 0.f}};

        float M[6][7];
        float PS[3][3], BS[3][3];
        #pragma unroll
        for (int i = 0; i < 3; ++i)
            #pragma unroll
            for (int j = 0; j < 3; ++j) {
                float s1 = 0.f, s2 = 0.f;
                #pragma unroll
                for (int k = 0; k < 3; ++k) { s1 += A[i][3+k]*S[k][j]; s2 += A[3+i][3+k]*S[k][j]; }
                PS[i][j] = s1; BS[i][j] = s2;
            }
        #pragma unroll
        for (int i = 0; i < 3; ++i)
            #pragma unroll
            for (int j = 0; j < 3; ++j) {
                float st = 0.f;
                #pragma unroll
                for (int k = 0; k < 3; ++k) st += S[k][i]*BS[k][j];
                M[i][j] = A[i][j] + PS[i][j] + PS[j][i] + st;
            }
        #pragma unroll
        for (int i = 0; i < 3; ++i)
            #pragma unroll
            for (int j = 0; j < 3; ++j) {
                float tr = A[i][3+j];
                #pragma unroll
                for (int k = 0; k < 3; ++k) tr += S[k][i]*A[3+k][3+j];
                M[i][3+j] = tr; M[3+j][i] = tr;
            }
        #pragma unroll
        for (int i = 0; i < 3; ++i)
            #pragma unroll
            for (int j = 0; j < 3; ++j) M[3+i][3+j] = A[3+i][3+j];
        #pragma unroll
        for (int d_ = 0; d_ < 6; ++d_) M[d_][d_] += damping;

        float base[6];
        #pragma unroll
        for (int s = 0; s < 6; ++s) {
            float v = q0[s];
            #pragma unroll
            for (int c = 0; c < 3; ++c) v -= tau[c]*R0[c][s];
            base[s] = v;
        }
        #pragma unroll
        for (int s = 0; s < 3; ++s) {
            float v = base[s];
            #pragma unroll
            for (int k = 0; k < 3; ++k) v += S[k][s]*base[3+k];
            M[s][6] = v;
        }
        #pragma unroll
        for (int s = 3; s < 6; ++s) M[s][6] = base[s];

        // pivot-free Gaussian elimination (SPD: damping>0 => nonzero pivots)
        #pragma unroll
        for (int col = 0; col < 6; ++col) {
            const float inv = 1.0f / M[col][col];
            #pragma unroll
            for (int r = col+1; r < 6; ++r) {
                const float f = M[r][col]*inv;
                #pragma unroll
                for (int cc = col; cc < 7; ++cc) M[r][cc] -= f*M[col][cc];
            }
        }
        float sol[6];
        #pragma unroll
        for (int r = 5; r >= 0; --r) {
            float s = M[r][6];
            #pragma unroll
            for (int cc = r+1; cc < 6; ++cc) s -= M[r][cc]*sol[cc];
            sol[r] = s / M[r][r];
        }
        #pragma unroll
        for (int s = 0; s < 6; ++s) x[s] += sol[s];
    }
    #pragma unroll
    for (int s = 0; s < 6; ++s) out[b*6 + s] = x[s];
}

extern "C" void kernel_launch(void* const* d_in, const int* in_sizes, int n_in,
                              void* d_out, int out_size, void* d_ws, size_t ws_size,
                              hipStream_t stream)
{
    (void)in_sizes; (void)n_in; (void)out_size; (void)ws_size;
    const float* f_inp = (const float*)d_in[0];
    const float* x_ini = (const float*)d_in[1];
    const float* depth = (const float*)d_in[2];
    const int*   fidx  = (const int*)  d_in[3];
    const float* Kmat  = (const float*)d_in[4];
    const float* bbox  = (const float*)d_in[5];
    const float* Wp    = (const float*)d_in[6];
    const float* bfeat = (const float*)d_in[7];
    const float* lam   = (const float*)d_in[8];
    float* out = (float*)d_out;

    float* partials = (float*)d_ws;

    dim3 gB(NBLK, BATCH);
    k_moments<<<gB, NTHR, 0, stream>>>(f_inp, depth, fidx, Kmat, bbox, bfeat, partials);
    k_solve<<<1, 256, 0, stream>>>(partials, x_ini, Wp, lam, out);
}

// Round 3
// 54.590 us; speedup vs baseline: 1.8348x; 1.1158x over previous
//
#include <hip/hip_runtime.h>
#include <math.h>

#define BATCH 32
#define CCH 3
#define HH 256
#define WW 256
#define HW (HH*WW)
#define NGN_IT 5
#define NM 45            // 21 (A sym 6x6) + 6 (q0) + 18 (R0 3x6)
#define NBLK 32
#define NTHR 256
#define PPQ 2            // quads per thread (8 pixels)

__host__ __device__ constexpr int idxA(int i, int j) { return 6*i - i*(i+1)/2 + j; } // i<=j

// ---------------------------------------------------------------------------
// Stage 1: per-(batch, block) partial moments. Deterministic (no atomics).
// Each thread owns PPQ quads of 4 contiguous pixels -> float4 loads.
//   A[i][j]  = sum_{p,c} J0[c,i]*J0[c,j]          (sym, 21)
//   q0[s]    = sum_{p,c} J0[c,s]*d[c]             (6),  d = f_inp - base_feat
//   R0[c][s] = sum_{p}   J0[c,s]                  (18)
// launch_bounds(,2): ~2 blocks/CU, VGPR budget up to 256 -> acc[45]+temps
// live in VGPRs, no AGPR ping-pong (round-2 kernel was pinned at 64 VGPRs).
// ---------------------------------------------------------------------------
__global__ __launch_bounds__(NTHR, 2) void k_moments(
    const float* __restrict__ f_inp, const float* __restrict__ depth,
    const int* __restrict__ fidx, const float* __restrict__ Kmat,
    const float* __restrict__ bbox, const float* __restrict__ base_feat,
    float* __restrict__ partials)
{
    const int b   = blockIdx.y;
    const int blk = blockIdx.x;
    const int tid = threadIdx.x;

    const float fx = Kmat[b*9+0], fy = Kmat[b*9+4];
    const float cx = Kmat[b*9+2], cy = Kmat[b*9+5];
    const float bb0 = bbox[b*2+0], bb1 = bbox[b*2+1];
    const float* __restrict__ dpt = depth + (size_t)b*HW;
    const int*   __restrict__ msk = fidx  + (size_t)b*HW;
    const float* __restrict__ fin = f_inp + (size_t)b*CCH*HW;

    float acc[NM];
    #pragma unroll
    for (int k = 0; k < NM; ++k) acc[k] = 0.f;

    #pragma unroll
    for (int it = 0; it < PPQ; ++it) {
        const int qid = blk*NTHR + tid + it*(NBLK*NTHR);
        const int p0  = qid * 4;            // first pixel of quad (16B aligned)
        const int h   = p0 >> 8;
        const int w0  = p0 & (WW-1);        // 0..252, multiple of 4

        const float4 zv = *(const float4*)(dpt + p0);
        const int4   mv = *(const int4*)(msk + p0);
        const float zq[4] = {zv.x, zv.y, zv.z, zv.w};
        const float mq[4] = {mv.x >= 0 ? 1.f : 0.f, mv.y >= 0 ? 1.f : 0.f,
                             mv.z >= 0 ? 1.f : 0.f, mv.w >= 0 ? 1.f : 0.f};

        const float sy  = (h == 0 || h == HH-1) ? 1.0f : 0.5f;
        const float sx0 = (w0 == 0)     ? 1.0f : 0.5f;
        const float sx3 = (w0 == WW-4)  ? 1.0f : 0.5f;

        float gxq[CCH][4], gyq[CCH][4], dq[CCH][4];
        #pragma unroll
        for (int c = 0; c < CCH; ++c) {
            const float* __restrict__ bfc = base_feat + (size_t)c*HW;
            const float4 cv4 = *(const float4*)(bfc + p0);
            const float cc0 = cv4.x, cc1 = cv4.y, cc2 = cv4.z, cc3 = cv4.w;
            const float lf = (w0 == 0)    ? cc0 : bfc[p0 - 1];
            const float rt = (w0 == WW-4) ? cc3 : bfc[p0 + 4];
            const float4 up4 = (h == HH-1) ? cv4 : *(const float4*)(bfc + p0 + WW);
            const float4 dn4 = (h == 0)    ? cv4 : *(const float4*)(bfc + p0 - WW);
            const float4 fv4 = *(const float4*)(fin + (size_t)c*HW + p0);
            gxq[c][0] = (cc1 - lf ) * sx0;
            gxq[c][1] = (cc2 - cc0) * 0.5f;
            gxq[c][2] = (cc3 - cc1) * 0.5f;
            gxq[c][3] = (rt  - cc2) * sx3;
            gyq[c][0] = (up4.x - dn4.x) * sy;
            gyq[c][1] = (up4.y - dn4.y) * sy;
            gyq[c][2] = (up4.z - dn4.z) * sy;
            gyq[c][3] = (up4.w - dn4.w) * sy;
            dq[c][0] = fv4.x - cc0; dq[c][1] = fv4.y - cc1;
            dq[c][2] = fv4.z - cc2; dq[c][3] = fv4.w - cc3;
        }

        const float dv_ = bb1 + (float)h - cy;
        #pragma unroll
        for (int j = 0; j < 4; ++j) {
            const float z = zq[j];
            const float inv_z = 1.0f / z;
            const float du = bb0 + (float)(w0 + j) - cx;
            const float a_ = fx*inv_z, b_ = fy*inv_z;       // Jp[0][0], Jp[1][1]
            const float cu = -du*inv_z, cv = -dv_*inv_z;    // Jp[0][2], Jp[1][2]
            const float xc = du*z/fx, yc = dv_*z/fy;
            // Jc0 = [-Jp*S(xc,yc,z) | Jp], rows:
            const float r00 = cu*yc;
            const float r01 = a_*z - cu*xc;
            const float r02 = -a_*yc;
            const float r10 = cv*yc - b_*z;
            const float r11 = -cv*xc;
            const float r12 = b_*xc;
            const float m = mq[j];
            #pragma unroll
            for (int c = 0; c < CCH; ++c) {
                const float gx = gxq[c][j] * m;
                const float gy = gyq[c][j] * m;
                const float d  = dq[c][j];
                float J0[6];
                J0[0] = gx*r00 + gy*r10;
                J0[1] = gx*r01 + gy*r11;
                J0[2] = gx*r02 + gy*r12;
                J0[3] = gx*a_;
                J0[4] = gy*b_;
                J0[5] = gx*cu + gy*cv;
                #pragma unroll
                for (int i = 0; i < 6; ++i)
                    #pragma unroll
                    for (int jj = i; jj < 6; ++jj)
                        acc[idxA(i,jj)] += J0[i]*J0[jj];
                #pragma unroll
                for (int s = 0; s < 6; ++s) acc[21 + s] += J0[s]*d;
                #pragma unroll
                for (int s = 0; s < 6; ++s) acc[27 + c*6 + s] += J0[s];
            }
        }
    }

    // block reduction: wave shuffle tree (deterministic) then 4-wave sum
    __shared__ float red[4*NM];
    const int lane = tid & 63;
    const int wave = tid >> 6;
    #pragma unroll
    for (int k = 0; k < NM; ++k) {
        float v = acc[k];
        #pragma unroll
        for (int off = 32; off > 0; off >>= 1) v += __shfl_down(v, off, 64);
        if (lane == 0) red[wave*NM + k] = v;
    }
    __syncthreads();
    if (tid < NM) {
        float s = red[tid] + red[NM + tid] + red[2*NM + tid] + red[3*NM + tid];
        // layout [b][k][blk] so k_solve's per-moment reduction is contiguous
        partials[((size_t)b*NM + tid)*NBLK + blk] = s;
    }
}

// ---------------------------------------------------------------------------
// Stage 2: one block per batch. Threads 0..44 reduce the 32 block partials
// (contiguous, fp64 sum). Thread 0 then runs the 5 GN iterations in fp32
// (dx ~ 1e-5; JtJ SPD => pivot-free elimination).
// ---------------------------------------------------------------------------
__global__ __launch_bounds__(64) void k_solve(
    const float* __restrict__ partials,
    const float* __restrict__ x_ini,
    const float* __restrict__ W_pose,
    const float* __restrict__ lam,
    float* __restrict__ out)
{
    const int b = blockIdx.x;
    const int tid = threadIdx.x;
    __shared__ float mom[NM];

    if (tid < NM) {
        const float* p = partials + ((size_t)b*NM + tid)*NBLK;
        double s = 0.0;
        #pragma unroll
        for (int i = 0; i < NBLK; ++i) s += (double)p[i];
        mom[tid] = (float)s;
    }
    __syncthreads();
    if (tid != 0) return;

    float A[6][6];
    for (int i = 0; i < 6; ++i)
        for (int j = i; j < 6; ++j) { float v = mom[idxA(i,j)]; A[i][j] = v; A[j][i] = v; }
    float q0[6];
    for (int s = 0; s < 6; ++s) q0[s] = mom[21 + s];
    float R0[3][6];
    for (int c = 0; c < 3; ++c) for (int s = 0; s < 6; ++s) R0[c][s] = mom[27 + c*6 + s];
    float Wp[3][6];
    for (int c = 0; c < 3; ++c) for (int s = 0; s < 6; ++s) Wp[c][s] = W_pose[c*6 + s];
    float x[6];
    for (int s = 0; s < 6; ++s) x[s] = x_ini[b*6 + s];
    const float damping = log1pf(expf(lam[0])) + 1e-6f;

    for (int it = 0; it < NGN_IT; ++it) {
        float tau[3];
        #pragma unroll
        for (int c = 0; c < 3; ++c) {
            float a = 0.f;
            #pragma unroll
            for (int s = 0; s < 6; ++s) a += x[s]*Wp[c][s];
            tau[c] = tanhf(a);
        }
        const float t0 = x[3], t1 = x[4], t2 = x[5];
        const float S[3][3] = {{0.f, -t2, t1}, {t2, 0.f, -t0}, {-t1, t0, 0.f}};

        float M[6][7];
        float PS[3][3], BS[3][3];
        #pragma unroll
        for (int i = 0; i < 3; ++i)
            #pragma unroll
            for (int j = 0; j < 3; ++j) {
                float s1 = 0.f, s2 = 0.f;
                #pragma unroll
                for (int k = 0; k < 3; ++k) { s1 += A[i][3+k]*S[k][j]; s2 += A[3+i][3+k]*S[k][j]; }
                PS[i][j] = s1; BS[i][j] = s2;
            }
        #pragma unroll
        for (int i = 0; i < 3; ++i)
            #pragma unroll
            for (int j = 0; j < 3; ++j) {
                float st = 0.f;
                #pragma unroll
                for (int k = 0; k < 3; ++k) st += S[k][i]*BS[k][j];
                M[i][j] = A[i][j] + PS[i][j] + PS[j][i] + st;
            }
        #pragma unroll
        for (int i = 0; i < 3; ++i)
            #pragma unroll
            for (int j = 0; j < 3; ++j) {
                float tr = A[i][3+j];
                #pragma unroll
                for (int k = 0; k < 3; ++k) tr += S[k][i]*A[3+k][3+j];
                M[i][3+j] = tr; M[3+j][i] = tr;
            }
        #pragma unroll
        for (int i = 0; i < 3; ++i)
            #pragma unroll
            for (int j = 0; j < 3; ++j) M[3+i][3+j] = A[3+i][3+j];
        #pragma unroll
        for (int d_ = 0; d_ < 6; ++d_) M[d_][d_] += damping;

        float base[6];
        #pragma unroll
        for (int s = 0; s < 6; ++s) {
            float v = q0[s];
            #pragma unroll
            for (int c = 0; c < 3; ++c) v -= tau[c]*R0[c][s];
            base[s] = v;
        }
        #pragma unroll
        for (int s = 0; s < 3; ++s) {
            float v = base[s];
            #pragma unroll
            for (int k = 0; k < 3; ++k) v += S[k][s]*base[3+k];
            M[s][6] = v;
        }
        #pragma unroll
        for (int s = 3; s < 6; ++s) M[s][6] = base[s];

        // pivot-free Gaussian elimination (SPD: damping>0 => nonzero pivots)
        #pragma unroll
        for (int col = 0; col < 6; ++col) {
            const float inv = 1.0f / M[col][col];
            #pragma unroll
            for (int r = col+1; r < 6; ++r) {
                const float f = M[r][col]*inv;
                #pragma unroll
                for (int cc = col; cc < 7; ++cc) M[r][cc] -= f*M[col][cc];
            }
        }
        float sol[6];
        #pragma unroll
        for (int r = 5; r >= 0; --r) {
            float s = M[r][6];
            #pragma unroll
            for (int cc = r+1; cc < 6; ++cc) s -= M[r][cc]*sol[cc];
            sol[r] = s / M[r][r];
        }
        #pragma unroll
        for (int s = 0; s < 6; ++s) x[s] += sol[s];
    }
    #pragma unroll
    for (int s = 0; s < 6; ++s) out[b*6 + s] = x[s];
}

extern "C" void kernel_launch(void* const* d_in, const int* in_sizes, int n_in,
                              void* d_out, int out_size, void* d_ws, size_t ws_size,
                              hipStream_t stream)
{
    (void)in_sizes; (void)n_in; (void)out_size; (void)ws_size;
    const float* f_inp = (const float*)d_in[0];
    const float* x_ini = (const float*)d_in[1];
    const float* depth = (const float*)d_in[2];
    const int*   fidx  = (const int*)  d_in[3];
    const float* Kmat  = (const float*)d_in[4];
    const float* bbox  = (const float*)d_in[5];
    const float* Wp    = (const float*)d_in[6];
    const float* bfeat = (const float*)d_in[7];
    const float* lam   = (const float*)d_in[8];
    float* out = (float*)d_out;

    float* partials = (float*)d_ws;

    dim3 gB(NBLK, BATCH);
    k_moments<<<gB, NTHR, 0, stream>>>(f_inp, depth, fidx, Kmat, bbox, bfeat, partials);
    k_solve<<<BATCH, 64, 0, stream>>>(partials, x_ini, Wp, lam, out);
}

// Round 4
// 47.889 us; speedup vs baseline: 2.0916x; 1.1399x over previous
//
#include <hip/hip_runtime.h>
#include <math.h>

#define BATCH 32
#define CCH 3
#define HH 256
#define WW 256
#define HW (HH*WW)
#define NGN_IT 5
#define NM 45            // 21 (A sym 6x6) + 6 (q0) + 18 (R0 3x6)
#define TROWS 4          // tile rows per block
#define NTILE (HH/TROWS) // 64 tiles per batch
#define NTHR 256

__host__ __device__ constexpr int idxA(int i, int j) { return 6*i - i*(i+1)/2 + j; } // i<=j

typedef __attribute__((address_space(1))) const unsigned int gu32;
typedef __attribute__((address_space(3))) unsigned int lu32;

__device__ __forceinline__ void gload_lds16(const float* g, float* l) {
    // per-lane global src; wave-uniform LDS base; HW writes lane i -> l + i*16
    __builtin_amdgcn_global_load_lds((gu32*)g, (lu32*)l, 16, 0, 0);
}

// ---------------------------------------------------------------------------
// Stage 1: block = 4-row tile of one batch. base_feat halo tile staged to LDS
// via global_load_lds (zero VGPR landing); depth/mask/f_inp loaded direct to
// registers (single-use). One vmcnt drain at the barrier -> one latency
// exposure per wave. Deterministic shuffle-tree reduction.
// ---------------------------------------------------------------------------
__global__ __launch_bounds__(NTHR, 4) void k_moments(
    const float* __restrict__ f_inp, const float* __restrict__ depth,
    const int* __restrict__ fidx, const float* __restrict__ Kmat,
    const float* __restrict__ bbox, const float* __restrict__ base_feat,
    float* __restrict__ partials)
{
    const int b   = blockIdx.y;
    const int h0  = blockIdx.x * TROWS;
    const int tid = threadIdx.x;

    __shared__ float bf_s[CCH][TROWS+2][WW];   // 18 KB (halo rows clamped)
    __shared__ float red[4*NM];

    // --- stage base_feat rows h0-1 .. h0+TROWS (clamped) ---
    const int wv = tid >> 6, ln = tid & 63;
    for (int o = wv; o < CCH*(TROWS+2); o += 4) {
        const int c = o / (TROWS+2), k = o % (TROWS+2);
        int srow = h0 - 1 + k;
        srow = srow < 0 ? 0 : (srow > HH-1 ? HH-1 : srow);
        gload_lds16(base_feat + ((size_t)c*HH + srow)*WW + ln*4, &bf_s[c][k][0]);
    }

    // --- direct per-thread loads (issued before barrier; latency overlaps) ---
    const int lp = tid * 4;          // local pixel 0..1023
    const int lr = lp >> 8;          // local row 0..3
    const int w0 = lp & (WW-1);      // col, multiple of 4
    const int h  = h0 + lr;
    const int p0 = h*WW + w0;
    const float4 zv = *(const float4*)(depth + (size_t)b*HW + p0);
    const int4   mv = *(const int4*)(fidx + (size_t)b*HW + p0);
    const float* __restrict__ finb = f_inp + (size_t)b*CCH*HW;
    const float4 fv0 = *(const float4*)(finb + p0);
    const float4 fv1 = *(const float4*)(finb + HW + p0);
    const float4 fv2 = *(const float4*)(finb + 2*HW + p0);

    const float fxv = Kmat[b*9+0], fyv = Kmat[b*9+4];
    const float cx  = Kmat[b*9+2], cy  = Kmat[b*9+5];
    const float bb0 = bbox[b*2+0], bb1 = bbox[b*2+1];
    const float ifx = 1.0f/fxv, ify = 1.0f/fyv;

    __syncthreads();   // drains vmcnt(0): LDS tile + reg loads all ready

    float acc[NM];
    #pragma unroll
    for (int k = 0; k < NM; ++k) acc[k] = 0.f;

    // per-row constants
    const float dv_ = bb1 + (float)h - cy;
    const float sy  = (h == 0 || h == HH-1) ? 1.0f : 0.5f;
    const float dvf = dv_*ify;
    const float r02 = -fxv*dvf;             // z-free Jacobian terms
    const float r10 = -(fyv + dv_*dvf);
    const float dvx = dv_*ifx;
    const float fyx = fyv*ifx;

    // per-pixel precompute (z-free algebra: all divisions removed)
    const float zq[4] = {zv.x, zv.y, zv.z, zv.w};
    const float mq[4] = {mv.x >= 0 ? 1.f : 0.f, mv.y >= 0 ? 1.f : 0.f,
                         mv.z >= 0 ? 1.f : 0.f, mv.w >= 0 ? 1.f : 0.f};
    float r00p[4], r01p[4], r11p[4], r12p[4], ap[4], bp[4], cup[4], cvp[4];
    #pragma unroll
    for (int j = 0; j < 4; ++j) {
        const float du = bb0 + (float)(w0 + j) - cx;
        const float iz = __builtin_amdgcn_rcpf(zq[j]);
        r00p[j] = -du*dvf;
        r01p[j] = fxv + du*du*ifx;
        r11p[j] = du*dvx;
        r12p[j] = du*fyx;
        ap[j]  = fxv*iz;
        bp[j]  = fyv*iz;
        cup[j] = -du*iz;
        cvp[j] = -dv_*iz;
    }

    const float sxl = (w0 == 0)    ? 1.0f : 0.5f;
    const float sxr = (w0 == WW-4) ? 1.0f : 0.5f;
    const int wl = (w0 == 0)    ? 0      : w0-1;
    const int wr = (w0 == WW-4) ? WW-1   : w0+4;

    #pragma unroll
    for (int c = 0; c < CCH; ++c) {
        const float4 ct = *(const float4*)&bf_s[c][lr+1][w0];
        const float4 up = *(const float4*)&bf_s[c][lr+2][w0];
        const float4 dn = *(const float4*)&bf_s[c][lr  ][w0];
        const float lf = bf_s[c][lr+1][wl];
        const float rt = bf_s[c][lr+1][wr];
        const float4 fvc = (c == 0) ? fv0 : (c == 1) ? fv1 : fv2;
        const float gx[4] = { (ct.y - lf  )*sxl, (ct.z - ct.x)*0.5f,
                              (ct.w - ct.y)*0.5f, (rt  - ct.z)*sxr };
        const float gy[4] = { (up.x - dn.x)*sy, (up.y - dn.y)*sy,
                              (up.z - dn.z)*sy, (up.w - dn.w)*sy };
        const float dd[4] = { fvc.x - ct.x, fvc.y - ct.y,
                              fvc.z - ct.z, fvc.w - ct.w };
        #pragma unroll
        for (int j = 0; j < 4; ++j) {
            const float gxm = gx[j]*mq[j];
            const float gym = gy[j]*mq[j];
            const float d   = dd[j];
            float J0[6];
            J0[0] = gxm*r00p[j] + gym*r10;
            J0[1] = gxm*r01p[j] + gym*r11p[j];
            J0[2] = gxm*r02     + gym*r12p[j];
            J0[3] = gxm*ap[j];
            J0[4] = gym*bp[j];
            J0[5] = gxm*cup[j] + gym*cvp[j];
            #pragma unroll
            for (int i = 0; i < 6; ++i)
                #pragma unroll
                for (int jj = i; jj < 6; ++jj)
                    acc[idxA(i,jj)] += J0[i]*J0[jj];
            #pragma unroll
            for (int s = 0; s < 6; ++s) acc[21 + s] += J0[s]*d;
            #pragma unroll
            for (int s = 0; s < 6; ++s) acc[27 + c*6 + s] += J0[s];
        }
    }

    // block reduction: wave shuffle tree (deterministic) then 4-wave sum
    #pragma unroll
    for (int k = 0; k < NM; ++k) {
        float v = acc[k];
        #pragma unroll
        for (int off = 32; off > 0; off >>= 1) v += __shfl_down(v, off, 64);
        if (ln == 0) red[wv*NM + k] = v;
    }
    __syncthreads();
    if (tid < NM) {
        float s = red[tid] + red[NM + tid] + red[2*NM + tid] + red[3*NM + tid];
        // layout [b][k][tile] so k_solve's per-moment reduction is contiguous
        partials[((size_t)b*NM + tid)*NTILE + blockIdx.x] = s;
    }
}

// ---------------------------------------------------------------------------
// Stage 2: one block per batch. Threads 0..44 reduce the tile partials
// (contiguous, fp64 sum). Thread 0 runs the 5 GN iterations in fp32
// (dx ~ 1e-5; JtJ SPD => pivot-free elimination).
// ---------------------------------------------------------------------------
__global__ __launch_bounds__(64) void k_solve(
    const float* __restrict__ partials,
    const float* __restrict__ x_ini,
    const float* __restrict__ W_pose,
    const float* __restrict__ lam,
    float* __restrict__ out)
{
    const int b = blockIdx.x;
    const int tid = threadIdx.x;
    __shared__ float mom[NM];

    if (tid < NM) {
        const float* p = partials + ((size_t)b*NM + tid)*NTILE;
        double s = 0.0;
        #pragma unroll
        for (int i = 0; i < NTILE; ++i) s += (double)p[i];
        mom[tid] = (float)s;
    }
    __syncthreads();
    if (tid != 0) return;

    float A[6][6];
    for (int i = 0; i < 6; ++i)
        for (int j = i; j < 6; ++j) { float v = mom[idxA(i,j)]; A[i][j] = v; A[j][i] = v; }
    float q0[6];
    for (int s = 0; s < 6; ++s) q0[s] = mom[21 + s];
    float R0[3][6];
    for (int c = 0; c < 3; ++c) for (int s = 0; s < 6; ++s) R0[c][s] = mom[27 + c*6 + s];
    float Wp[3][6];
    for (int c = 0; c < 3; ++c) for (int s = 0; s < 6; ++s) Wp[c][s] = W_pose[c*6 + s];
    float x[6];
    for (int s = 0; s < 6; ++s) x[s] = x_ini[b*6 + s];
    const float damping = log1pf(expf(lam[0])) + 1e-6f;

    for (int it = 0; it < NGN_IT; ++it) {
        float tau[3];
        #pragma unroll
        for (int c = 0; c < 3; ++c) {
            float a = 0.f;
            #pragma unroll
            for (int s = 0; s < 6; ++s) a += x[s]*Wp[c][s];
            tau[c] = tanhf(a);
        }
        const float t0 = x[3], t1 = x[4], t2 = x[5];
        const float S[3][3] = {{0.f, -t2, t1}, {t2, 0.f, -t0}, {-t1, t0, 0.f}};

        float M[6][7];
        float PS[3][3], BS[3][3];
        #pragma unroll
        for (int i = 0; i < 3; ++i)
            #pragma unroll
            for (int j = 0; j < 3; ++j) {
                float s1 = 0.f, s2 = 0.f;
                #pragma unroll
                for (int k = 0; k < 3; ++k) { s1 += A[i][3+k]*S[k][j]; s2 += A[3+i][3+k]*S[k][j]; }
                PS[i][j] = s1; BS[i][j] = s2;
            }
        #pragma unroll
        for (int i = 0; i < 3; ++i)
            #pragma unroll
            for (int j = 0; j < 3; ++j) {
                float st = 0.f;
                #pragma unroll
                for (int k = 0; k < 3; ++k) st += S[k][i]*BS[k][j];
                M[i][j] = A[i][j] + PS[i][j] + PS[j][i] + st;
            }
        #pragma unroll
        for (int i = 0; i < 3; ++i)
            #pragma unroll
            for (int j = 0; j < 3; ++j) {
                float tr = A[i][3+j];
                #pragma unroll
                for (int k = 0; k < 3; ++k) tr += S[k][i]*A[3+k][3+j];
                M[i][3+j] = tr; M[3+j][i] = tr;
            }
        #pragma unroll
        for (int i = 0; i < 3; ++i)
            #pragma unroll
            for (int j = 0; j < 3; ++j) M[3+i][3+j] = A[3+i][3+j];
        #pragma unroll
        for (int d_ = 0; d_ < 6; ++d_) M[d_][d_] += damping;

        float base[6];
        #pragma unroll
        for (int s = 0; s < 6; ++s) {
            float v = q0[s];
            #pragma unroll
            for (int c = 0; c < 3; ++c) v -= tau[c]*R0[c][s];
            base[s] = v;
        }
        #pragma unroll
        for (int s = 0; s < 3; ++s) {
            float v = base[s];
            #pragma unroll
            for (int k = 0; k < 3; ++k) v += S[k][s]*base[3+k];
            M[s][6] = v;
        }
        #pragma unroll
        for (int s = 3; s < 6; ++s) M[s][6] = base[s];

        // pivot-free Gaussian elimination (SPD: damping>0 => nonzero pivots)
        #pragma unroll
        for (int col = 0; col < 6; ++col) {
            const float inv = 1.0f / M[col][col];
            #pragma unroll
            for (int r = col+1; r < 6; ++r) {
                const float f = M[r][col]*inv;
                #pragma unroll
                for (int cc = col; cc < 7; ++cc) M[r][cc] -= f*M[col][cc];
            }
        }
        float sol[6];
        #pragma unroll
        for (int r = 5; r >= 0; --r) {
            float s = M[r][6];
            #pragma unroll
            for (int cc = r+1; cc < 6; ++cc) s -= M[r][cc]*sol[cc];
            sol[r] = s / M[r][r];
        }
        #pragma unroll
        for (int s = 0; s < 6; ++s) x[s] += sol[s];
    }
    #pragma unroll
    for (int s = 0; s < 6; ++s) out[b*6 + s] = x[s];
}

extern "C" void kernel_launch(void* const* d_in, const int* in_sizes, int n_in,
                              void* d_out, int out_size, void* d_ws, size_t ws_size,
                              hipStream_t stream)
{
    (void)in_sizes; (void)n_in; (void)out_size; (void)ws_size;
    const float* f_inp = (const float*)d_in[0];
    const float* x_ini = (const float*)d_in[1];
    const float* depth = (const float*)d_in[2];
    const int*   fidx  = (const int*)  d_in[3];
    const float* Kmat  = (const float*)d_in[4];
    const float* bbox  = (const float*)d_in[5];
    const float* Wp    = (const float*)d_in[6];
    const float* bfeat = (const float*)d_in[7];
    const float* lam   = (const float*)d_in[8];
    float* out = (float*)d_out;

    float* partials = (float*)d_ws;

    dim3 gB(NTILE, BATCH);
    k_moments<<<gB, NTHR, 0, stream>>>(f_inp, depth, fidx, Kmat, bbox, bfeat, partials);
    k_solve<<<BATCH, 64, 0, stream>>>(partials, x_ini, Wp, lam, out);
}

// Round 5
// 46.666 us; speedup vs baseline: 2.1464x; 1.0262x over previous
//
#include <hip/hip_runtime.h>
#include <math.h>

#define BATCH 32
#define CCH 3
#define HH 256
#define WW 256
#define HW (HH*WW)
#define NGN_IT 5
#define NM 45            // 21 (A sym 6x6) + 6 (q0) + 18 (R0 3x6)
#define TROWS 4          // tile rows per block
#define NTILE (HH/TROWS) // 64 tiles per batch
#define NTHR 256

__host__ __device__ constexpr int idxA(int i, int j) { return 6*i - i*(i+1)/2 + j; } // i<=j

typedef __attribute__((address_space(1))) const unsigned int gu32;
typedef __attribute__((address_space(3))) unsigned int lu32;

__device__ __forceinline__ void gload_lds16(const float* g, float* l) {
    // per-lane global src; wave-uniform LDS base; HW writes lane i -> l + i*16
    __builtin_amdgcn_global_load_lds((gu32*)g, (lu32*)l, 16, 0, 0);
}

// ---------------------------------------------------------------------------
// Stage 1: block = 4-row tile of one batch. base_feat halo tile in LDS via
// global_load_lds (zero VGPR landing); depth/mask/f_inp direct to registers.
// Register-pressure-shaped: c-outer/j-inner, gx/gy/d computed on the fly,
// geometry recomputed per (c,j) from row constants + iz[4]. Target ~110 live
// VGPRs so acc[45] never spills to AGPR/scratch (rounds 2-4 all spilled).
// ---------------------------------------------------------------------------
__global__ __launch_bounds__(NTHR, 3) void k_moments(
    const float* __restrict__ f_inp, const float* __restrict__ depth,
    const int* __restrict__ fidx, const float* __restrict__ Kmat,
    const float* __restrict__ bbox, const float* __restrict__ base_feat,
    float* __restrict__ partials)
{
    const int b   = blockIdx.y;
    const int h0  = blockIdx.x * TROWS;
    const int tid = threadIdx.x;

    __shared__ float bf_s[CCH][TROWS+2][WW];   // 18 KB (halo rows clamped)
    __shared__ float red[4*NM];

    // --- stage base_feat rows h0-1 .. h0+TROWS (clamped) ---
    const int wv = tid >> 6, ln = tid & 63;
    for (int o = wv; o < CCH*(TROWS+2); o += 4) {
        const int c = o / (TROWS+2), k = o % (TROWS+2);
        int srow = h0 - 1 + k;
        srow = srow < 0 ? 0 : (srow > HH-1 ? HH-1 : srow);
        gload_lds16(base_feat + ((size_t)c*HH + srow)*WW + ln*4, &bf_s[c][k][0]);
    }

    // --- direct per-thread loads (issued before barrier; latency overlaps) ---
    const int lp = tid * 4;          // local pixel 0..1023
    const int lr = lp >> 8;          // local row 0..3
    const int w0 = lp & (WW-1);      // col, multiple of 4
    const int h  = h0 + lr;
    const int p0 = h*WW + w0;
    const float4 zv = *(const float4*)(depth + (size_t)b*HW + p0);
    const int4   mv = *(const int4*)(fidx + (size_t)b*HW + p0);
    const float* __restrict__ finb = f_inp + (size_t)b*CCH*HW;
    const float4 fv0 = *(const float4*)(finb + p0);
    const float4 fv1 = *(const float4*)(finb + HW + p0);
    const float4 fv2 = *(const float4*)(finb + 2*HW + p0);

    const float fxv = Kmat[b*9+0], fyv = Kmat[b*9+4];
    const float cx  = Kmat[b*9+2], cy  = Kmat[b*9+5];
    const float bb0 = bbox[b*2+0], bb1 = bbox[b*2+1];
    const float ifx = __builtin_amdgcn_rcpf(fxv);
    const float ify = __builtin_amdgcn_rcpf(fyv);

    // per-thread precompute that frees its sources
    float iz[4];
    iz[0] = __builtin_amdgcn_rcpf(zv.x);
    iz[1] = __builtin_amdgcn_rcpf(zv.y);
    iz[2] = __builtin_amdgcn_rcpf(zv.z);
    iz[3] = __builtin_amdgcn_rcpf(zv.w);
    float mq[4];
    mq[0] = mv.x >= 0 ? 1.f : 0.f; mq[1] = mv.y >= 0 ? 1.f : 0.f;
    mq[2] = mv.z >= 0 ? 1.f : 0.f; mq[3] = mv.w >= 0 ? 1.f : 0.f;

    // row constants (z-free Jacobian algebra)
    const float dv_ = bb1 + (float)h - cy;
    const float sy  = (h == 0 || h == HH-1) ? 1.0f : 0.5f;
    const float dvf = dv_*ify;
    const float r02 = -fxv*dvf;
    const float r10 = -(fyv + dv_*dvf);
    const float dvx = dv_*ifx;
    const float fyx = fyv*ifx;
    const float duB = bb0 + (float)w0 - cx;
    const float sx0 = (w0 == 0)    ? 1.0f : 0.5f;
    const float sx3 = (w0 == WW-4) ? 1.0f : 0.5f;
    const int wl = (w0 == 0)    ? 0    : w0-1;
    const int wr = (w0 == WW-4) ? WW-1 : w0+4;

    __syncthreads();   // drains vmcnt(0): LDS tile ready

    float acc[NM];
    #pragma unroll
    for (int k = 0; k < NM; ++k) acc[k] = 0.f;

    #pragma unroll
    for (int c = 0; c < CCH; ++c) {
        const float4 ct = *(const float4*)&bf_s[c][lr+1][w0];
        const float4 up = *(const float4*)&bf_s[c][lr+2][w0];
        const float4 dn = *(const float4*)&bf_s[c][lr  ][w0];
        const float lf = bf_s[c][lr+1][wl];
        const float rt = bf_s[c][lr+1][wr];
        const float4 fvc = (c == 0) ? fv0 : (c == 1) ? fv1 : fv2;
        #pragma unroll
        for (int j = 0; j < 4; ++j) {
            const float gx  = (j==0) ? (ct.y - lf  )*sx0 :
                              (j==1) ? (ct.z - ct.x)*0.5f :
                              (j==2) ? (ct.w - ct.y)*0.5f :
                                       (rt   - ct.z)*sx3;
            const float gyv = ((j==0) ? (up.x - dn.x) :
                               (j==1) ? (up.y - dn.y) :
                               (j==2) ? (up.z - dn.z) :
                                        (up.w - dn.w)) * sy;
            const float fc  = (j==0) ? fvc.x : (j==1) ? fvc.y : (j==2) ? fvc.z : fvc.w;
            const float ctj = (j==0) ? ct.x  : (j==1) ? ct.y  : (j==2) ? ct.z  : ct.w;
            const float d   = fc - ctj;
            const float gxm = gx  * mq[j];
            const float gym = gyv * mq[j];
            const float du  = duB + (float)j;
            const float izj = iz[j];
            float J0[6];
            J0[0] = gxm*(-du*dvf)            + gym*r10;
            J0[1] = gxm*(fxv + du*du*ifx)    + gym*(du*dvx);
            J0[2] = gxm*r02                  + gym*(du*fyx);
            J0[3] = gxm*(fxv*izj);
            J0[4] = gym*(fyv*izj);
            J0[5] = -(gxm*du + gym*dv_)*izj;
            #pragma unroll
            for (int i = 0; i < 6; ++i)
                #pragma unroll
                for (int jj = i; jj < 6; ++jj)
                    acc[idxA(i,jj)] += J0[i]*J0[jj];
            #pragma unroll
            for (int s = 0; s < 6; ++s) acc[21 + s] += J0[s]*d;
            #pragma unroll
            for (int s = 0; s < 6; ++s) acc[27 + c*6 + s] += J0[s];
        }
    }

    // block reduction: wave shuffle tree (deterministic) then 4-wave sum
    #pragma unroll
    for (int k = 0; k < NM; ++k) {
        float v = acc[k];
        #pragma unroll
        for (int off = 32; off > 0; off >>= 1) v += __shfl_down(v, off, 64);
        if (ln == 0) red[wv*NM + k] = v;
    }
    __syncthreads();
    if (tid < NM) {
        float s = red[tid] + red[NM + tid] + red[2*NM + tid] + red[3*NM + tid];
        // layout [b][k][tile] so k_solve's per-moment reduction is contiguous
        partials[((size_t)b*NM + tid)*NTILE + blockIdx.x] = s;
    }
}

// ---------------------------------------------------------------------------
// Stage 2: one block per batch. Threads 0..44 reduce the tile partials
// (contiguous, fp64 sum). Thread 0 runs the 5 GN iterations in fp32
// (dx ~ 1e-5; JtJ SPD => pivot-free elimination).
// ---------------------------------------------------------------------------
__global__ __launch_bounds__(64) void k_solve(
    const float* __restrict__ partials,
    const float* __restrict__ x_ini,
    const float* __restrict__ W_pose,
    const float* __restrict__ lam,
    float* __restrict__ out)
{
    const int b = blockIdx.x;
    const int tid = threadIdx.x;
    __shared__ float mom[NM];

    if (tid < NM) {
        const float* p = partials + ((size_t)b*NM + tid)*NTILE;
        double s = 0.0;
        #pragma unroll
        for (int i = 0; i < NTILE; ++i) s += (double)p[i];
        mom[tid] = (float)s;
    }
    __syncthreads();
    if (tid != 0) return;

    float A[6][6];
    for (int i = 0; i < 6; ++i)
        for (int j = i; j < 6; ++j) { float v = mom[idxA(i,j)]; A[i][j] = v; A[j][i] = v; }
    float q0[6];
    for (int s = 0; s < 6; ++s) q0[s] = mom[21 + s];
    float R0[3][6];
    for (int c = 0; c < 3; ++c) for (int s = 0; s < 6; ++s) R0[c][s] = mom[27 + c*6 + s];
    float Wp[3][6];
    for (int c = 0; c < 3; ++c) for (int s = 0; s < 6; ++s) Wp[c][s] = W_pose[c*6 + s];
    float x[6];
    for (int s = 0; s < 6; ++s) x[s] = x_ini[b*6 + s];
    const float damping = log1pf(expf(lam[0])) + 1e-6f;

    for (int it = 0; it < NGN_IT; ++it) {
        float tau[3];
        #pragma unroll
        for (int c = 0; c < 3; ++c) {
            float a = 0.f;
            #pragma unroll
            for (int s = 0; s < 6; ++s) a += x[s]*Wp[c][s];
            tau[c] = tanhf(a);
        }
        const float t0 = x[3], t1 = x[4], t2 = x[5];
        const float S[3][3] = {{0.f, -t2, t1}, {t2, 0.f, -t0}, {-t1, t0, 0.f}};

        float M[6][7];
        float PS[3][3], BS[3][3];
        #pragma unroll
        for (int i = 0; i < 3; ++i)
            #pragma unroll
            for (int j = 0; j < 3; ++j) {
                float s1 = 0.f, s2 = 0.f;
                #pragma unroll
                for (int k = 0; k < 3; ++k) { s1 += A[i][3+k]*S[k][j]; s2 += A[3+i][3+k]*S[k][j]; }
                PS[i][j] = s1; BS[i][j] = s2;
            }
        #pragma unroll
        for (int i = 0; i < 3; ++i)
            #pragma unroll
            for (int j = 0; j < 3; ++j) {
                float st = 0.f;
                #pragma unroll
                for (int k = 0; k < 3; ++k) st += S[k][i]*BS[k][j];
                M[i][j] = A[i][j] + PS[i][j] + PS[j][i] + st;
            }
        #pragma unroll
        for (int i = 0; i < 3; ++i)
            #pragma unroll
            for (int j = 0; j < 3; ++j) {
                float tr = A[i][3+j];
                #pragma unroll
                for (int k = 0; k < 3; ++k) tr += S[k][i]*A[3+k][3+j];
                M[i][3+j] = tr; M[3+j][i] = tr;
            }
        #pragma unroll
        for (int i = 0; i < 3; ++i)
            #pragma unroll
            for (int j = 0; j < 3; ++j) M[3+i][3+j] = A[3+i][3+j];
        #pragma unroll
        for (int d_ = 0; d_ < 6; ++d_) M[d_][d_] += damping;

        float base[6];
        #pragma unroll
        for (int s = 0; s < 6; ++s) {
            float v = q0[s];
            #pragma unroll
            for (int c = 0; c < 3; ++c) v -= tau[c]*R0[c][s];
            base[s] = v;
        }
        #pragma unroll
        for (int s = 0; s < 3; ++s) {
            float v = base[s];
            #pragma unroll
            for (int k = 0; k < 3; ++k) v += S[k][s]*base[3+k];
            M[s][6] = v;
        }
        #pragma unroll
        for (int s = 3; s < 6; ++s) M[s][6] = base[s];

        // pivot-free Gaussian elimination (SPD: damping>0 => nonzero pivots)
        #pragma unroll
        for (int col = 0; col < 6; ++col) {
            const float inv = 1.0f / M[col][col];
            #pragma unroll
            for (int r = col+1; r < 6; ++r) {
                const float f = M[r][col]*inv;
                #pragma unroll
                for (int cc = col; cc < 7; ++cc) M[r][cc] -= f*M[col][cc];
            }
        }
        float sol[6];
        #pragma unroll
        for (int r = 5; r >= 0; --r) {
            float s = M[r][6];
            #pragma unroll
            for (int cc = r+1; cc < 6; ++cc) s -= M[r][cc]*sol[cc];
            sol[r] = s / M[r][r];
        }
        #pragma unroll
        for (int s = 0; s < 6; ++s) x[s] += sol[s];
    }
    #pragma unroll
    for (int s = 0; s < 6; ++s) out[b*6 + s] = x[s];
}

extern "C" void kernel_launch(void* const* d_in, const int* in_sizes, int n_in,
                              void* d_out, int out_size, void* d_ws, size_t ws_size,
                              hipStream_t stream)
{
    (void)in_sizes; (void)n_in; (void)out_size; (void)ws_size;
    const float* f_inp = (const float*)d_in[0];
    const float* x_ini = (const float*)d_in[1];
    const float* depth = (const float*)d_in[2];
    const int*   fidx  = (const int*)  d_in[3];
    const float* Kmat  = (const float*)d_in[4];
    const float* bbox  = (const float*)d_in[5];
    const float* Wp    = (const float*)d_in[6];
    const float* bfeat = (const float*)d_in[7];
    const float* lam   = (const float*)d_in[8];
    float* out = (float*)d_out;

    float* partials = (float*)d_ws;

    dim3 gB(NTILE, BATCH);
    k_moments<<<gB, NTHR, 0, stream>>>(f_inp, depth, fidx, Kmat, bbox, bfeat, partials);
    k_solve<<<BATCH, 64, 0, stream>>>(partials, x_ini, Wp, lam, out);
}